// Round 13
// baseline (170.971 us; speedup 1.0000x reference)
//
#include <hip/hip_runtime.h>
#include <hip/hip_fp16.h>

#define NEG_SLOPE 0.2f
#define BSHIFT 6          // bucket = 64 consecutive dst ids
#define SCATB 256         // blocks in count/scatter phases

__device__ __forceinline__ float elu1(float v) { return v > 0.f ? v : expm1f(v); }
__device__ __forceinline__ float lrelu(float v) { return v > 0.f ? v : NEG_SLOPE * v; }

// global exclusive offset of scan element j, from scan1 partials + scanned block sums
__device__ __forceinline__ int ge_off(const int* __restrict__ blkoff,
                                      const int* __restrict__ bsum2, int j) {
    if (j == 0) return 0;
    int b = (j - 1) >> 8;            // scan1 block of element j-1 (256/block)
    int v = blkoff[j];
    if (b >= 1) v += bsum2[b - 1];
    return v;
}

// ---------------- CSR build: exact-offset bucketing (no global atomics) ----------------

// Fused: blocks [0,SCATB) bucket histogram; [SCATB, SCATB+nAttn) attn1+record pack.
__global__ __launch_bounds__(256) void k_cnt_attn(
    const int* __restrict__ ei, int E, int ET, int chunk,
    int* __restrict__ Cmat, int nbuck,
    const float* __restrict__ x, const float* __restrict__ W1,
    const float* __restrict__ att_s, const float* __restrict__ att_d,
    __half* __restrict__ rech, float4* __restrict__ ad4f, int N,
    int* __restrict__ done) {
    __shared__ int hist[784];
    __shared__ float Ps[5][4], Pd[5][4];
    if (blockIdx.x < SCATB) {
        for (int i = threadIdx.x; i < nbuck; i += 256) hist[i] = 0;
        __syncthreads();
        int k = blockIdx.x;
        int e0 = k * chunk, e1 = min(e0 + chunk, ET);
        for (int e = e0 + threadIdx.x; e < e1; e += 256) {
            int d = (e < E) ? ei[E + e] : e - E;
            atomicAdd(&hist[d >> BSHIFT], 1);
        }
        __syncthreads();
        for (int i = threadIdx.x; i < nbuck; i += 256)
            Cmat[i * SCATB + k] = hist[i];
    } else {
        if (blockIdx.x == SCATB && threadIdx.x == 0) *done = 0;  // reset scan flag
        // ---- attn1: packed 32B fp16 record rech[16] = {as0..3, x0..4, pad} ----
        if (threadIdx.x < 40) {
            int pair = threadIdx.x & 1, idx = threadIdx.x >> 1;
            int k = idx >> 2, h = idx & 3;
            const float* att = pair ? att_d : att_s;
            float r = 0.f;
#pragma unroll
            for (int c = 0; c < 32; ++c) r = fmaf(W1[k * 128 + h * 32 + c], att[h * 32 + c], r);
            if (pair) Pd[k][h] = r; else Ps[k][h] = r;
        }
        __syncthreads();
        int n = (blockIdx.x - SCATB) * 256 + threadIdx.x;
        if (n >= N) return;
        float xv[5];
#pragma unroll
        for (int k = 0; k < 5; ++k) xv[k] = x[(size_t)n * 5 + k];
        float s0 = 0, s1 = 0, s2 = 0, s3 = 0, d0 = 0, d1 = 0, d2 = 0, d3 = 0;
#pragma unroll
        for (int k = 0; k < 5; ++k) {
            s0 = fmaf(xv[k], Ps[k][0], s0); s1 = fmaf(xv[k], Ps[k][1], s1);
            s2 = fmaf(xv[k], Ps[k][2], s2); s3 = fmaf(xv[k], Ps[k][3], s3);
            d0 = fmaf(xv[k], Pd[k][0], d0); d1 = fmaf(xv[k], Pd[k][1], d1);
            d2 = fmaf(xv[k], Pd[k][2], d2); d3 = fmaf(xv[k], Pd[k][3], d3);
        }
        __half2 a[4], b[4];
        a[0] = __floats2half2_rn(s0, s1);
        a[1] = __floats2half2_rn(s2, s3);
        a[2] = __floats2half2_rn(xv[0], xv[1]);
        a[3] = __floats2half2_rn(xv[2], xv[3]);
        b[0] = __floats2half2_rn(xv[4], 0.f);
        b[1] = b[2] = b[3] = __floats2half2_rn(0.f, 0.f);
        *(float4*)(rech + (size_t)n * 16)     = *(float4*)a;
        *(float4*)(rech + (size_t)n * 16 + 8) = *(float4*)b;
        ad4f[n] = make_float4(d0, d1, d2, d3);
    }
}

// per-block inclusive scan -> blkoff[i+1] (partial), totals -> bsum; the LAST
// block to finish then scans bsum in-place (inclusive). Values deterministic.
__global__ __launch_bounds__(256) void k_scan1f(
    const int* __restrict__ Cmat, int* __restrict__ blkoff, int* __restrict__ bsum,
    int M, int* __restrict__ done, int* __restrict__ off, int N, int ET) {
    __shared__ int ws4[4], wsoff[4];
    __shared__ int lastDone;
    int i = blockIdx.x * 256 + threadIdx.x;
    int lane = threadIdx.x & 63, w = threadIdx.x >> 6;
    int v = (i < M) ? Cmat[i] : 0;
    int sc = v;
#pragma unroll
    for (int m = 1; m < 64; m <<= 1) {
        int t = __shfl_up(sc, m, 64);
        if (lane >= m) sc += t;
    }
    if (lane == 63) ws4[w] = sc;
    __syncthreads();
    if (threadIdx.x == 0) {
        int r = 0;
#pragma unroll
        for (int j = 0; j < 4; ++j) { wsoff[j] = r; r += ws4[j]; }
        __hip_atomic_store(&bsum[blockIdx.x], r, __ATOMIC_RELEASE, __HIP_MEMORY_SCOPE_AGENT);
    }
    __syncthreads();
    if (i < M) blkoff[i + 1] = sc + wsoff[w];
    if (i == 0) { blkoff[0] = 0; off[N] = ET; }
    // ---- last-block level-2 scan of bsum (nb = gridDim.x <= 1024) ----
    __threadfence();
    if (threadIdx.x == 0)
        lastDone = (__hip_atomic_fetch_add(done, 1, __ATOMIC_ACQ_REL,
                                           __HIP_MEMORY_SCOPE_AGENT) == (int)gridDim.x - 1);
    __syncthreads();
    if (!lastDone) return;
    int nb = gridDim.x;
    int t = threadIdx.x;
    int vv[4], ssum = 0;
#pragma unroll
    for (int j = 0; j < 4; ++j) {
        int idx = t * 4 + j;
        vv[j] = (idx < nb) ? __hip_atomic_load(&bsum[idx], __ATOMIC_RELAXED,
                                               __HIP_MEMORY_SCOPE_AGENT) : 0;
        ssum += vv[j];
    }
    int sc2 = ssum;
#pragma unroll
    for (int m = 1; m < 64; m <<= 1) {
        int u = __shfl_up(sc2, m, 64);
        if (lane >= m) sc2 += u;
    }
    __syncthreads();             // ws4/wsoff reuse
    if (lane == 63) ws4[w] = sc2;
    __syncthreads();
    if (threadIdx.x == 0) {
        int r = 0;
#pragma unroll
        for (int j = 0; j < 4; ++j) { wsoff[j] = r; r += ws4[j]; }
    }
    __syncthreads();
    int run = sc2 - ssum + wsoff[w];
#pragma unroll
    for (int j = 0; j < 4; ++j) {
        int idx = t * 4 + j;
        run += vv[j];
        if (idx < nb) bsum[idx] = run;   // inclusive
    }
}

__global__ __launch_bounds__(256) void k_scat(
    const int* __restrict__ ei, int E, int ET, int chunk,
    const int* __restrict__ blkoff, const int* __restrict__ bsum2,
    unsigned* __restrict__ pairs, int nbuck) {
    __shared__ int cur[784];
    int k = blockIdx.x;
    for (int i = threadIdx.x; i < nbuck; i += 256)
        cur[i] = ge_off(blkoff, bsum2, i * SCATB + k);
    __syncthreads();
    int e0 = k * chunk, e1 = min(e0 + chunk, ET);
    for (int e = e0 + threadIdx.x; e < e1; e += 256) {
        int s, d;
        if (e < E) { s = ei[e]; d = ei[E + e]; } else { s = d = e - E; }
        int p = atomicAdd(&cur[d >> BSHIFT], 1);
        pairs[p] = (unsigned)s | ((unsigned)(d & 63) << 16);   // src < 65536
    }
}

// per-bucket LDS counting sort, single pass over pairs (LDS-staged)
__global__ __launch_bounds__(256) void k_sortB(
    const unsigned* __restrict__ pairs, const int* __restrict__ blkoff,
    const int* __restrict__ bsum2, int* __restrict__ off,
    int* __restrict__ csr_src, int N, int ET, int nbuck) {
    __shared__ int hist[64], cur[64];
    __shared__ unsigned pl[1536];
    int b = blockIdx.x;
    int base = ge_off(blkoff, bsum2, b * SCATB);
    int end  = (b + 1 < nbuck) ? ge_off(blkoff, bsum2, (b + 1) * SCATB) : ET;
    int cnt = end - base;
    int stg = min(cnt, 1536);
    int dstBase = b << BSHIFT;
    if (threadIdx.x < 64) hist[threadIdx.x] = 0;
    for (int i = threadIdx.x; i < stg; i += 256) pl[i] = pairs[base + i];
    __syncthreads();
    for (int i = threadIdx.x; i < cnt; i += 256) {
        unsigned pr = (i < stg) ? pl[i] : pairs[base + i];
        atomicAdd(&hist[pr >> 16], 1);
    }
    __syncthreads();
    if (threadIdx.x < 64) {
        int v = hist[threadIdx.x], sc = v;
#pragma unroll
        for (int m = 1; m < 64; m <<= 1) {
            int t = __shfl_up(sc, m, 64);
            if (threadIdx.x >= m) sc += t;
        }
        int ex = sc - v;
        cur[threadIdx.x] = ex;
        int d = dstBase + threadIdx.x;
        if (d < N) off[d] = base + ex;
    }
    __syncthreads();
    for (int i = threadIdx.x; i < cnt; i += 256) {
        unsigned pr = (i < stg) ? pl[i] : pairs[base + i];
        int r = atomicAdd(&cur[pr >> 16], 1);
        csr_src[base + r] = (int)(pr & 0xFFFFu);
    }
}

// ---------------- layer 1 ----------------

// 8-lane group per dst (was 16): gathers 32B fp16 records, 3-step butterfly
// (24 values), fused expand; lane l owns head l>>1 and channels l*16..l*16+15.
__global__ __launch_bounds__(256) void k_agg1(
    const int* __restrict__ off, const int* __restrict__ csr_src,
    const __half* __restrict__ rech, const float4* __restrict__ ad4f,
    const float* __restrict__ W1, const float* __restrict__ b1,
    __half* __restrict__ out1h, int N) {
    __shared__ float Wl[5 * 128];
    __shared__ float b1l[128];
    for (int i = threadIdx.x; i < 5 * 128; i += 256) Wl[i] = W1[i];
    if (threadIdx.x < 128) b1l[threadIdx.x] = b1[threadIdx.x];
    __syncthreads();
    int g = (blockIdx.x * 256 + threadIdx.x) >> 3;
    int lane = threadIdx.x & 7;
    if (g >= N) return;
    int p0 = off[g], p1 = off[g + 1];
    float4 ad = ad4f[g];
    float den0 = 0, den1 = 0, den2 = 0, den3 = 0;
    float acc[4][5] = {};
    for (int p = p0 + lane; p < p1; p += 8) {
        int s = csr_src[p];
        const __half* r = rech + (size_t)s * 16;
        float4 q = *(const float4*)r;          // halves 0..7: as0..3, x0..3
        const __half2* hp = (const __half2*)&q;
        float2 as01 = __half22float2(hp[0]);
        float2 as23 = __half22float2(hp[1]);
        float2 x01  = __half22float2(hp[2]);
        float2 x23  = __half22float2(hp[3]);
        float  x4   = __half2float(r[8]);
        float v0 = __expf(lrelu(as01.x + ad.x));
        float v1 = __expf(lrelu(as01.y + ad.y));
        float v2 = __expf(lrelu(as23.x + ad.z));
        float v3 = __expf(lrelu(as23.y + ad.w));
        den0 += v0; den1 += v1; den2 += v2; den3 += v3;
        float xk[5] = {x01.x, x01.y, x23.x, x23.y, x4};
#pragma unroll
        for (int k = 0; k < 5; ++k) {
            acc[0][k] = fmaf(v0, xk[k], acc[0][k]);
            acc[1][k] = fmaf(v1, xk[k], acc[1][k]);
            acc[2][k] = fmaf(v2, xk[k], acc[2][k]);
            acc[3][k] = fmaf(v3, xk[k], acc[3][k]);
        }
    }
#pragma unroll
    for (int m = 4; m; m >>= 1) {
        den0 += __shfl_xor(den0, m, 8); den1 += __shfl_xor(den1, m, 8);
        den2 += __shfl_xor(den2, m, 8); den3 += __shfl_xor(den3, m, 8);
#pragma unroll
        for (int h = 0; h < 4; ++h)
#pragma unroll
            for (int k = 0; k < 5; ++k) acc[h][k] += __shfl_xor(acc[h][k], m, 8);
    }
    int h = lane >> 1;
    float dh = (h == 0) ? den0 : (h == 1) ? den1 : (h == 2) ? den2 : den3;
    float ih = 1.f / dh;
    float ag[5];
#pragma unroll
    for (int k = 0; k < 5; ++k) {
        float av = (h == 0) ? acc[0][k] : (h == 1) ? acc[1][k]
                 : (h == 2) ? acc[2][k] : acc[3][k];
        ag[k] = av * ih;
    }
    int c0 = lane * 16;
    __half2 ph[8];
#pragma unroll
    for (int j = 0; j < 8; ++j) {
        int c = c0 + 2 * j;
        float rr = b1l[c];
#pragma unroll
        for (int k = 0; k < 5; ++k) rr = fmaf(ag[k], Wl[k * 128 + c], rr);
        float oa = elu1(rr);
        rr = b1l[c + 1];
#pragma unroll
        for (int k = 0; k < 5; ++k) rr = fmaf(ag[k], Wl[k * 128 + c + 1], rr);
        float ob = elu1(rr);
        ph[j] = __floats2half2_rn(oa, ob);
    }
    float4* op = (float4*)(out1h + (size_t)g * 128 + c0);
    op[0] = ((float4*)ph)[0];
    op[1] = ((float4*)ph)[1];
}

// ---------------- layer 2 ----------------

// h2 = out1 @ W2 (128 -> 32) + attention dots. W2 in LDS as fp16 transposed.
__global__ __launch_bounds__(256) void k_feat2(
    const __half* __restrict__ out1h, const float* __restrict__ W2,
    const float* __restrict__ att_s, const float* __restrict__ att_d,
    __half* __restrict__ h2h, float* __restrict__ a_s, float* __restrict__ a_d, int N) {
    __shared__ __half Wt[32 * 132];
    for (int i = threadIdx.x; i < 4096; i += 256) {
        int k = i >> 5, c = i & 31;
        Wt[c * 132 + k] = __float2half_rn(W2[i]);
    }
    __syncthreads();
    int t = blockIdx.x * 256 + threadIdx.x;
    int n = t >> 5, c = t & 31;
    if (n >= N) return;
    const float4* hr4 = (const float4*)(out1h + (size_t)n * 128);
    const __half2* wrow = (const __half2*)(Wt + c * 132);
    float acc = 0.f;
#pragma unroll
    for (int k4 = 0; k4 < 16; ++k4) {
        float4 q = hr4[k4];
        const __half2* hp = (const __half2*)&q;
#pragma unroll
        for (int m = 0; m < 4; ++m) {
            float2 f  = __half22float2(hp[m]);
            float2 wv = __half22float2(wrow[k4 * 4 + m]);
            acc = fmaf(f.x, wv.x, acc);
            acc = fmaf(f.y, wv.y, acc);
        }
    }
    h2h[(size_t)n * 32 + c] = __float2half_rn(acc);
    float as = acc * att_s[c], ad = acc * att_d[c];
#pragma unroll
    for (int m = 16; m; m >>= 1) {
        as += __shfl_xor(as, m, 32);
        ad += __shfl_xor(ad, m, 32);
    }
    if (c == 0) { a_s[n] = as; a_d[n] = ad; }
}

// ---------------- layer-2 aggregation + fused MLP head ----------------
// Per-edge (s,w) staged once in LDS per 32-edge chunk; inner loop reads 2
// edges per ds_read_b128 broadcast (replaces 2 ds_bpermute per edge).
__global__ __launch_bounds__(256) void k_agg2h(
    const int* __restrict__ off, const int* __restrict__ csr_src,
    const float* __restrict__ a_s, const float* __restrict__ a_d,
    const __half* __restrict__ h2h, const float* __restrict__ b2,
    const float* __restrict__ Wc1, const float* __restrict__ bc1,
    const float* __restrict__ Wc2, const float* __restrict__ bc2,
    float* __restrict__ out, int N) {
    __shared__ float Wl[512];
    __shared__ float b2l[32], b1l[16], w2l[16];
    __shared__ uint2 wsb[256];          // per-thread (s, w) staging
    for (int i = threadIdx.x; i < 512; i += 256) Wl[i] = Wc1[i];
    if (threadIdx.x < 32) b2l[threadIdx.x] = b2[threadIdx.x];
    if (threadIdx.x < 16) {
        b1l[threadIdx.x] = bc1[threadIdx.x];
        w2l[threadIdx.x] = Wc2[threadIdx.x];
    }
    __syncthreads();
    int g = (blockIdx.x * 256 + threadIdx.x) >> 5;
    int lane = threadIdx.x & 31;
    int gl = threadIdx.x >> 5;          // group index within block
    if (g >= N) return;
    int p0 = off[g], p1 = off[g + 1];
    float ad = a_d[g];
    float acc = 0.f, den = 0.f;
    const uint4* wp = (const uint4*)(wsb + (gl << 5));
    for (int base = p0; base < p1; base += 32) {
        int rem = p1 - base;
        int s = g;                 // safe index for padded lanes
        float w = 0.f;
        if (lane < rem) {
            s = csr_src[base + lane];           // coalesced
            w = __expf(lrelu(a_s[s] + ad));     // one exp per edge
        }
        den += w;
        wsb[threadIdx.x] = make_uint2((unsigned)s, __float_as_uint(w));
        // same-wave LDS write->read: in-order DS pipe, per-tid slots, no barrier
        int cnt = min(rem, 32);
        int rc = (cnt + 7) & ~7;   // pad to multiple of 8 (w=0 beyond cnt)
        for (int j = 0; j < rc; j += 8) {
#pragma unroll
            for (int jj = 0; jj < 4; ++jj) {
                uint4 q = wp[(j >> 1) + jj];    // 2 edges per b128 broadcast
                float w0 = __uint_as_float(q.y);
                float w1 = __uint_as_float(q.w);
                float h0 = __half2float(h2h[(size_t)q.x * 32 + lane]);
                float h1 = __half2float(h2h[(size_t)q.z * 32 + lane]);
                acc = fmaf(w0, h0, acc);
                acc = fmaf(w1, h1, acc);
            }
        }
    }
#pragma unroll
    for (int m = 16; m; m >>= 1) den += __shfl_xor(den, m, 32);
    float z = elu1(fmaf(acc, 1.f / den, b2l[lane]));
    float y = b1l[lane & 15];
#pragma unroll
    for (int c = 0; c < 32; ++c) {
        float zc = __shfl(z, c, 32);
        y = fmaf(zc, Wl[c * 16 + (lane & 15)], y);
    }
    y = fmaxf(y, 0.f);
    float t = (lane < 16) ? y * w2l[lane] : 0.f;
#pragma unroll
    for (int m = 8; m; m >>= 1) t += __shfl_xor(t, m, 32);
    if (lane == 0) out[g] = t + bc2[0];
}

extern "C" void kernel_launch(void* const* d_in, const int* in_sizes, int n_in,
                              void* d_out, int out_size, void* d_ws, size_t ws_size,
                              hipStream_t stream) {
    const float* x   = (const float*)d_in[0];
    const int*   ei  = (const int*)d_in[1];
    const float* W1  = (const float*)d_in[2];
    const float* as1 = (const float*)d_in[3];
    const float* ad1 = (const float*)d_in[4];
    const float* b1  = (const float*)d_in[5];
    const float* W2  = (const float*)d_in[6];
    const float* as2 = (const float*)d_in[7];
    const float* ad2 = (const float*)d_in[8];
    const float* b2  = (const float*)d_in[9];
    const float* Wc1 = (const float*)d_in[10];
    const float* bc1 = (const float*)d_in[11];
    const float* Wc2 = (const float*)d_in[12];
    const float* bc2 = (const float*)d_in[13];
    float* out = (float*)d_out;

    const int N = out_size;                  // 50000
    const int E = in_sizes[1] / 2;           // 800000
    const int ET = E + N;                    // + self loops
    const int nbuck = (N + 63) >> BSHIFT;    // 782
    const int M = nbuck * SCATB;             // 200192 scan elements
    const int chunk = (ET + SCATB - 1) / SCATB;

    auto cdiv = [](long long a, long long b) { return (int)((a + b - 1) / b); };
    const int B = 256;
    const int NB2 = cdiv(M, B);              // 782 <= 1024
    const int nAttn = cdiv(N, B);            // 196

    // Workspace layout (float units; all half counts even -> aligned)
    float*    ws    = (float*)d_ws;
    __half*   out1h = (__half*)ws;                       // N*128 halves (N*64 f)
    __half*   h2h   = (__half*)(ws + (size_t)N * 64);    // N*32 halves (N*16 f)
    __half*   rech  = (__half*)(ws + (size_t)N * 80);    // N*16 halves (N*8 f)
    float4*   ad4f  = (float4*)(ws + (size_t)N * 88);    // N float4
    float*    a_s2  = ws + (size_t)N * 92;               // N
    float*    a_d2  = a_s2 + N;                          // N
    int*      off   = (int*)(a_d2 + N);                  // N+1
    int*      csr_src = off + (N + 2);                   // ET
    int*      Cmat  = csr_src + ET;                      // M
    int*      blkoff = Cmat + M;                         // M+2
    int*      bsum  = blkoff + (M + 2);                  // 1024
    int*      done  = bsum + 1024;                       // 1 (+3 pad)
    unsigned* pairs = (unsigned*)(done + 4);             // ET

    // ---- CSR build (count+attn1 -> fused 2-level scan -> scatter -> sort) ----
    k_cnt_attn<<<SCATB + nAttn, B, 0, stream>>>(ei, E, ET, chunk, Cmat, nbuck,
                                                x, W1, as1, ad1, rech, ad4f, N, done);
    k_scan1f<<<NB2, B, 0, stream>>>(Cmat, blkoff, bsum, M, done, off, N, ET);
    k_scat<<<SCATB, B, 0, stream>>>(ei, E, ET, chunk, blkoff, bsum, pairs, nbuck);
    k_sortB<<<nbuck, B, 0, stream>>>(pairs, blkoff, bsum, off, csr_src, N, ET, nbuck);

    // ---- layer 1 (input-space aggregation, fused expand; 8 lanes/dst) ----
    k_agg1<<<cdiv((long long)N * 8, B), B, 0, stream>>>(off, csr_src, rech, ad4f,
                                                        W1, b1, out1h, N);

    // ---- layer 2 ----
    k_feat2<<<cdiv((long long)N * 32, B), B, 0, stream>>>(out1h, W2, as2, ad2, h2h,
                                                          a_s2, a_d2, N);
    k_agg2h<<<cdiv((long long)N * 32, B), B, 0, stream>>>(off, csr_src, a_s2, a_d2, h2h, b2,
                                                          Wc1, bc1, Wc2, bc2, out, N);
}

// Round 14
// 103.735 us; speedup vs baseline: 1.6481x; 1.6481x over previous
//
#include <hip/hip_runtime.h>
#include <hip/hip_fp16.h>

#define NEG_SLOPE 0.2f
#define BSHIFT 6          // bucket = 64 consecutive dst ids
#define SCATB 256         // blocks in count/scatter phases

__device__ __forceinline__ float elu1(float v) { return v > 0.f ? v : expm1f(v); }
__device__ __forceinline__ float lrelu(float v) { return v > 0.f ? v : NEG_SLOPE * v; }

// global exclusive offset of scan element j, from scan1 partials + scanned block sums
__device__ __forceinline__ int ge_off(const int* __restrict__ blkoff,
                                      const int* __restrict__ bsum2, int j) {
    if (j == 0) return 0;
    int b = (j - 1) >> 8;            // scan1 block of element j-1 (256/block)
    int v = blkoff[j];
    if (b >= 1) v += bsum2[b - 1];
    return v;
}

// ---------------- CSR build: exact-offset bucketing (no global atomics) ----------------

// Fused: blocks [0,SCATB) bucket histogram; [SCATB, SCATB+nAttn) attn1+record pack.
__global__ __launch_bounds__(256) void k_cnt_attn(
    const int* __restrict__ ei, int E, int ET, int chunk,
    int* __restrict__ Cmat, int nbuck,
    const float* __restrict__ x, const float* __restrict__ W1,
    const float* __restrict__ att_s, const float* __restrict__ att_d,
    __half* __restrict__ rech, float4* __restrict__ ad4f, int N) {
    __shared__ int hist[784];
    __shared__ float Ps[5][4], Pd[5][4];
    if (blockIdx.x < SCATB) {
        for (int i = threadIdx.x; i < nbuck; i += 256) hist[i] = 0;
        __syncthreads();
        int k = blockIdx.x;
        int e0 = k * chunk, e1 = min(e0 + chunk, ET);
        for (int e = e0 + threadIdx.x; e < e1; e += 256) {
            int d = (e < E) ? ei[E + e] : e - E;
            atomicAdd(&hist[d >> BSHIFT], 1);
        }
        __syncthreads();
        for (int i = threadIdx.x; i < nbuck; i += 256)
            Cmat[i * SCATB + k] = hist[i];
    } else {
        // ---- attn1: packed 32B fp16 record rech[16] = {as0..3, x0..4, pad} ----
        if (threadIdx.x < 40) {
            int pair = threadIdx.x & 1, idx = threadIdx.x >> 1;
            int k = idx >> 2, h = idx & 3;
            const float* att = pair ? att_d : att_s;
            float r = 0.f;
#pragma unroll
            for (int c = 0; c < 32; ++c) r = fmaf(W1[k * 128 + h * 32 + c], att[h * 32 + c], r);
            if (pair) Pd[k][h] = r; else Ps[k][h] = r;
        }
        __syncthreads();
        int n = (blockIdx.x - SCATB) * 256 + threadIdx.x;
        if (n >= N) return;
        float xv[5];
#pragma unroll
        for (int k = 0; k < 5; ++k) xv[k] = x[(size_t)n * 5 + k];
        float s0 = 0, s1 = 0, s2 = 0, s3 = 0, d0 = 0, d1 = 0, d2 = 0, d3 = 0;
#pragma unroll
        for (int k = 0; k < 5; ++k) {
            s0 = fmaf(xv[k], Ps[k][0], s0); s1 = fmaf(xv[k], Ps[k][1], s1);
            s2 = fmaf(xv[k], Ps[k][2], s2); s3 = fmaf(xv[k], Ps[k][3], s3);
            d0 = fmaf(xv[k], Pd[k][0], d0); d1 = fmaf(xv[k], Pd[k][1], d1);
            d2 = fmaf(xv[k], Pd[k][2], d2); d3 = fmaf(xv[k], Pd[k][3], d3);
        }
        __half2 a[4], b[4];
        a[0] = __floats2half2_rn(s0, s1);
        a[1] = __floats2half2_rn(s2, s3);
        a[2] = __floats2half2_rn(xv[0], xv[1]);
        a[3] = __floats2half2_rn(xv[2], xv[3]);
        b[0] = __floats2half2_rn(xv[4], 0.f);
        b[1] = b[2] = b[3] = __floats2half2_rn(0.f, 0.f);
        *(float4*)(rech + (size_t)n * 16)     = *(float4*)a;
        *(float4*)(rech + (size_t)n * 16 + 8) = *(float4*)b;
        ad4f[n] = make_float4(d0, d1, d2, d3);
    }
}

// per-block inclusive scan -> blkoff[i+1] (partial), block totals -> bsum
__global__ __launch_bounds__(256) void k_scan1(
    const int* __restrict__ Cmat, int* __restrict__ blkoff, int* __restrict__ bsum, int M) {
    __shared__ int ws4[4], wsoff[4];
    int i = blockIdx.x * 256 + threadIdx.x;
    int lane = threadIdx.x & 63, w = threadIdx.x >> 6;
    int v = (i < M) ? Cmat[i] : 0;
    int sc = v;
#pragma unroll
    for (int m = 1; m < 64; m <<= 1) {
        int t = __shfl_up(sc, m, 64);
        if (lane >= m) sc += t;
    }
    if (lane == 63) ws4[w] = sc;
    __syncthreads();
    if (threadIdx.x == 0) {
        int r = 0;
#pragma unroll
        for (int j = 0; j < 4; ++j) { wsoff[j] = r; r += ws4[j]; }
        bsum[blockIdx.x] = r;
    }
    __syncthreads();
    if (i < M) blkoff[i + 1] = sc + wsoff[w];
    if (i == 0) blkoff[0] = 0;
}

// scan block totals (nb <= 1024), 16-wave block, inclusive in-place; also off[N]=ET
__global__ __launch_bounds__(1024) void k_scan2(
    int* __restrict__ bsum, int nb, int* __restrict__ off, int N, int ET) {
    __shared__ int wsum[16];
    int i = threadIdx.x, lane = i & 63, w = i >> 6;
    if (i == 0) off[N] = ET;
    int v = (i < nb) ? bsum[i] : 0, sc = v;
#pragma unroll
    for (int m = 1; m < 64; m <<= 1) {
        int t = __shfl_up(sc, m, 64);
        if (lane >= m) sc += t;
    }
    if (lane == 63) wsum[w] = sc;
    __syncthreads();
    if (w == 0 && lane < 16) {
        int s2 = wsum[lane];
#pragma unroll
        for (int m = 1; m < 16; m <<= 1) {
            int t = __shfl_up(s2, m, 16);
            if (lane >= m) s2 += t;
        }
        wsum[lane] = s2;
    }
    __syncthreads();
    int carry = (w == 0) ? 0 : wsum[w - 1];
    if (i < nb) bsum[i] = carry + sc;
}

__global__ __launch_bounds__(256) void k_scat(
    const int* __restrict__ ei, int E, int ET, int chunk,
    const int* __restrict__ blkoff, const int* __restrict__ bsum2,
    unsigned* __restrict__ pairs, int nbuck) {
    __shared__ int cur[784];
    int k = blockIdx.x;
    for (int i = threadIdx.x; i < nbuck; i += 256)
        cur[i] = ge_off(blkoff, bsum2, i * SCATB + k);
    __syncthreads();
    int e0 = k * chunk, e1 = min(e0 + chunk, ET);
    for (int e = e0 + threadIdx.x; e < e1; e += 256) {
        int s, d;
        if (e < E) { s = ei[e]; d = ei[E + e]; } else { s = d = e - E; }
        int p = atomicAdd(&cur[d >> BSHIFT], 1);
        pairs[p] = (unsigned)s | ((unsigned)(d & 63) << 16);   // src < 65536
    }
}

// per-bucket LDS counting sort, single pass over pairs (LDS-staged)
__global__ __launch_bounds__(256) void k_sortB(
    const unsigned* __restrict__ pairs, const int* __restrict__ blkoff,
    const int* __restrict__ bsum2, int* __restrict__ off,
    int* __restrict__ csr_src, int N, int ET, int nbuck) {
    __shared__ int hist[64], cur[64];
    __shared__ unsigned pl[1536];
    int b = blockIdx.x;
    int base = ge_off(blkoff, bsum2, b * SCATB);
    int end  = (b + 1 < nbuck) ? ge_off(blkoff, bsum2, (b + 1) * SCATB) : ET;
    int cnt = end - base;
    int stg = min(cnt, 1536);
    int dstBase = b << BSHIFT;
    if (threadIdx.x < 64) hist[threadIdx.x] = 0;
    for (int i = threadIdx.x; i < stg; i += 256) pl[i] = pairs[base + i];
    __syncthreads();
    for (int i = threadIdx.x; i < cnt; i += 256) {
        unsigned pr = (i < stg) ? pl[i] : pairs[base + i];
        atomicAdd(&hist[pr >> 16], 1);
    }
    __syncthreads();
    if (threadIdx.x < 64) {
        int v = hist[threadIdx.x], sc = v;
#pragma unroll
        for (int m = 1; m < 64; m <<= 1) {
            int t = __shfl_up(sc, m, 64);
            if (threadIdx.x >= m) sc += t;
        }
        int ex = sc - v;
        cur[threadIdx.x] = ex;
        int d = dstBase + threadIdx.x;
        if (d < N) off[d] = base + ex;
    }
    __syncthreads();
    for (int i = threadIdx.x; i < cnt; i += 256) {
        unsigned pr = (i < stg) ? pl[i] : pairs[base + i];
        int r = atomicAdd(&cur[pr >> 16], 1);
        csr_src[base + r] = (int)(pr & 0xFFFFu);
    }
}

// ---------------- layer 1 ----------------

// 8-lane group per dst: gathers 32B fp16 records, 3-step butterfly (24 values),
// fused expand; lane l owns head l>>1 and channels l*16..l*16+15.
__global__ __launch_bounds__(256) void k_agg1(
    const int* __restrict__ off, const int* __restrict__ csr_src,
    const __half* __restrict__ rech, const float4* __restrict__ ad4f,
    const float* __restrict__ W1, const float* __restrict__ b1,
    __half* __restrict__ out1h, int N) {
    __shared__ float Wl[5 * 128];
    __shared__ float b1l[128];
    for (int i = threadIdx.x; i < 5 * 128; i += 256) Wl[i] = W1[i];
    if (threadIdx.x < 128) b1l[threadIdx.x] = b1[threadIdx.x];
    __syncthreads();
    int g = (blockIdx.x * 256 + threadIdx.x) >> 3;
    int lane = threadIdx.x & 7;
    if (g >= N) return;
    int p0 = off[g], p1 = off[g + 1];
    float4 ad = ad4f[g];
    float den0 = 0, den1 = 0, den2 = 0, den3 = 0;
    float acc[4][5] = {};
    for (int p = p0 + lane; p < p1; p += 8) {
        int s = csr_src[p];
        const __half* r = rech + (size_t)s * 16;
        float4 q = *(const float4*)r;          // halves 0..7: as0..3, x0..3
        const __half2* hp = (const __half2*)&q;
        float2 as01 = __half22float2(hp[0]);
        float2 as23 = __half22float2(hp[1]);
        float2 x01  = __half22float2(hp[2]);
        float2 x23  = __half22float2(hp[3]);
        float  x4   = __half2float(r[8]);
        float v0 = __expf(lrelu(as01.x + ad.x));
        float v1 = __expf(lrelu(as01.y + ad.y));
        float v2 = __expf(lrelu(as23.x + ad.z));
        float v3 = __expf(lrelu(as23.y + ad.w));
        den0 += v0; den1 += v1; den2 += v2; den3 += v3;
        float xk[5] = {x01.x, x01.y, x23.x, x23.y, x4};
#pragma unroll
        for (int k = 0; k < 5; ++k) {
            acc[0][k] = fmaf(v0, xk[k], acc[0][k]);
            acc[1][k] = fmaf(v1, xk[k], acc[1][k]);
            acc[2][k] = fmaf(v2, xk[k], acc[2][k]);
            acc[3][k] = fmaf(v3, xk[k], acc[3][k]);
        }
    }
#pragma unroll
    for (int m = 4; m; m >>= 1) {
        den0 += __shfl_xor(den0, m, 8); den1 += __shfl_xor(den1, m, 8);
        den2 += __shfl_xor(den2, m, 8); den3 += __shfl_xor(den3, m, 8);
#pragma unroll
        for (int h = 0; h < 4; ++h)
#pragma unroll
            for (int k = 0; k < 5; ++k) acc[h][k] += __shfl_xor(acc[h][k], m, 8);
    }
    int h = lane >> 1;
    float dh = (h == 0) ? den0 : (h == 1) ? den1 : (h == 2) ? den2 : den3;
    float ih = 1.f / dh;
    float ag[5];
#pragma unroll
    for (int k = 0; k < 5; ++k) {
        float av = (h == 0) ? acc[0][k] : (h == 1) ? acc[1][k]
                 : (h == 2) ? acc[2][k] : acc[3][k];
        ag[k] = av * ih;
    }
    int c0 = lane * 16;
    __half2 ph[8];
#pragma unroll
    for (int j = 0; j < 8; ++j) {
        int c = c0 + 2 * j;
        float rr = b1l[c];
#pragma unroll
        for (int k = 0; k < 5; ++k) rr = fmaf(ag[k], Wl[k * 128 + c], rr);
        float oa = elu1(rr);
        rr = b1l[c + 1];
#pragma unroll
        for (int k = 0; k < 5; ++k) rr = fmaf(ag[k], Wl[k * 128 + c + 1], rr);
        float ob = elu1(rr);
        ph[j] = __floats2half2_rn(oa, ob);
    }
    float4* op = (float4*)(out1h + (size_t)g * 128 + c0);
    op[0] = ((float4*)ph)[0];
    op[1] = ((float4*)ph)[1];
}

// ---------------- layer 2 ----------------

// h2 = out1 @ W2 (128 -> 32) + attention dots. W2 in LDS as fp16 transposed.
__global__ __launch_bounds__(256) void k_feat2(
    const __half* __restrict__ out1h, const float* __restrict__ W2,
    const float* __restrict__ att_s, const float* __restrict__ att_d,
    __half* __restrict__ h2h, float* __restrict__ a_s, float* __restrict__ a_d, int N) {
    __shared__ __half Wt[32 * 132];
    for (int i = threadIdx.x; i < 4096; i += 256) {
        int k = i >> 5, c = i & 31;
        Wt[c * 132 + k] = __float2half_rn(W2[i]);
    }
    __syncthreads();
    int t = blockIdx.x * 256 + threadIdx.x;
    int n = t >> 5, c = t & 31;
    if (n >= N) return;
    const float4* hr4 = (const float4*)(out1h + (size_t)n * 128);
    const __half2* wrow = (const __half2*)(Wt + c * 132);
    float acc = 0.f;
#pragma unroll
    for (int k4 = 0; k4 < 16; ++k4) {
        float4 q = hr4[k4];
        const __half2* hp = (const __half2*)&q;
#pragma unroll
        for (int m = 0; m < 4; ++m) {
            float2 f  = __half22float2(hp[m]);
            float2 wv = __half22float2(wrow[k4 * 4 + m]);
            acc = fmaf(f.x, wv.x, acc);
            acc = fmaf(f.y, wv.y, acc);
        }
    }
    h2h[(size_t)n * 32 + c] = __float2half_rn(acc);
    float as = acc * att_s[c], ad = acc * att_d[c];
#pragma unroll
    for (int m = 16; m; m >>= 1) {
        as += __shfl_xor(as, m, 32);
        ad += __shfl_xor(ad, m, 32);
    }
    if (c == 0) { a_s[n] = as; a_d[n] = ad; }
}

// ---------------- layer-2 aggregation + fused MLP head ----------------
// Per-edge (s,w) staged once in LDS per 32-edge chunk; inner loop reads 2
// edges per ds_read_b128 broadcast (replaces 2 ds_bpermute per edge).
__global__ __launch_bounds__(256) void k_agg2h(
    const int* __restrict__ off, const int* __restrict__ csr_src,
    const float* __restrict__ a_s, const float* __restrict__ a_d,
    const __half* __restrict__ h2h, const float* __restrict__ b2,
    const float* __restrict__ Wc1, const float* __restrict__ bc1,
    const float* __restrict__ Wc2, const float* __restrict__ bc2,
    float* __restrict__ out, int N) {
    __shared__ float Wl[512];
    __shared__ float b2l[32], b1l[16], w2l[16];
    __shared__ uint2 wsb[256];          // per-thread (s, w) staging
    for (int i = threadIdx.x; i < 512; i += 256) Wl[i] = Wc1[i];
    if (threadIdx.x < 32) b2l[threadIdx.x] = b2[threadIdx.x];
    if (threadIdx.x < 16) {
        b1l[threadIdx.x] = bc1[threadIdx.x];
        w2l[threadIdx.x] = Wc2[threadIdx.x];
    }
    __syncthreads();
    int g = (blockIdx.x * 256 + threadIdx.x) >> 5;
    int lane = threadIdx.x & 31;
    int gl = threadIdx.x >> 5;          // group index within block
    if (g >= N) return;
    int p0 = off[g], p1 = off[g + 1];
    float ad = a_d[g];
    float acc = 0.f, den = 0.f;
    const uint4* wp = (const uint4*)(wsb + (gl << 5));
    for (int base = p0; base < p1; base += 32) {
        int rem = p1 - base;
        int s = g;                 // safe index for padded lanes
        float w = 0.f;
        if (lane < rem) {
            s = csr_src[base + lane];           // coalesced
            w = __expf(lrelu(a_s[s] + ad));     // one exp per edge
        }
        den += w;
        wsb[threadIdx.x] = make_uint2((unsigned)s, __float_as_uint(w));
        // same-wave LDS write->read: in-order DS pipe, per-tid slots, no barrier
        int cnt = min(rem, 32);
        int rc = (cnt + 7) & ~7;   // pad to multiple of 8 (w=0 beyond cnt)
        for (int j = 0; j < rc; j += 8) {
#pragma unroll
            for (int jj = 0; jj < 4; ++jj) {
                uint4 q = wp[(j >> 1) + jj];    // 2 edges per b128 broadcast
                float w0 = __uint_as_float(q.y);
                float w1 = __uint_as_float(q.w);
                float h0 = __half2float(h2h[(size_t)q.x * 32 + lane]);
                float h1 = __half2float(h2h[(size_t)q.z * 32 + lane]);
                acc = fmaf(w0, h0, acc);
                acc = fmaf(w1, h1, acc);
            }
        }
    }
#pragma unroll
    for (int m = 16; m; m >>= 1) den += __shfl_xor(den, m, 32);
    float z = elu1(fmaf(acc, 1.f / den, b2l[lane]));
    float y = b1l[lane & 15];
#pragma unroll
    for (int c = 0; c < 32; ++c) {
        float zc = __shfl(z, c, 32);
        y = fmaf(zc, Wl[c * 16 + (lane & 15)], y);
    }
    y = fmaxf(y, 0.f);
    float t = (lane < 16) ? y * w2l[lane] : 0.f;
#pragma unroll
    for (int m = 8; m; m >>= 1) t += __shfl_xor(t, m, 32);
    if (lane == 0) out[g] = t + bc2[0];
}

extern "C" void kernel_launch(void* const* d_in, const int* in_sizes, int n_in,
                              void* d_out, int out_size, void* d_ws, size_t ws_size,
                              hipStream_t stream) {
    const float* x   = (const float*)d_in[0];
    const int*   ei  = (const int*)d_in[1];
    const float* W1  = (const float*)d_in[2];
    const float* as1 = (const float*)d_in[3];
    const float* ad1 = (const float*)d_in[4];
    const float* b1  = (const float*)d_in[5];
    const float* W2  = (const float*)d_in[6];
    const float* as2 = (const float*)d_in[7];
    const float* ad2 = (const float*)d_in[8];
    const float* b2  = (const float*)d_in[9];
    const float* Wc1 = (const float*)d_in[10];
    const float* bc1 = (const float*)d_in[11];
    const float* Wc2 = (const float*)d_in[12];
    const float* bc2 = (const float*)d_in[13];
    float* out = (float*)d_out;

    const int N = out_size;                  // 50000
    const int E = in_sizes[1] / 2;           // 800000
    const int ET = E + N;                    // + self loops
    const int nbuck = (N + 63) >> BSHIFT;    // 782
    const int M = nbuck * SCATB;             // 200192 scan elements
    const int chunk = (ET + SCATB - 1) / SCATB;

    auto cdiv = [](long long a, long long b) { return (int)((a + b - 1) / b); };
    const int B = 256;
    const int NB2 = cdiv(M, B);              // 782 <= 1024
    const int nAttn = cdiv(N, B);            // 196

    // Workspace layout (float units; all half counts even -> aligned)
    float*    ws    = (float*)d_ws;
    __half*   out1h = (__half*)ws;                       // N*128 halves (N*64 f)
    __half*   h2h   = (__half*)(ws + (size_t)N * 64);    // N*32 halves (N*16 f)
    __half*   rech  = (__half*)(ws + (size_t)N * 80);    // N*16 halves (N*8 f)
    float4*   ad4f  = (float4*)(ws + (size_t)N * 88);    // N float4
    float*    a_s2  = ws + (size_t)N * 92;               // N
    float*    a_d2  = a_s2 + N;                          // N
    int*      off   = (int*)(a_d2 + N);                  // N+1
    int*      csr_src = off + (N + 2);                   // ET
    int*      Cmat  = csr_src + ET;                      // M
    int*      blkoff = Cmat + M;                         // M+2
    int*      bsum  = blkoff + (M + 2);                  // 1024
    unsigned* pairs = (unsigned*)(bsum + 1024);          // ET

    // ---- CSR build (count+attn1 -> 2-level scan -> scatter -> sort) ----
    k_cnt_attn<<<SCATB + nAttn, B, 0, stream>>>(ei, E, ET, chunk, Cmat, nbuck,
                                                x, W1, as1, ad1, rech, ad4f, N);
    k_scan1<<<NB2, B, 0, stream>>>(Cmat, blkoff, bsum, M);
    k_scan2<<<1, 1024, 0, stream>>>(bsum, NB2, off, N, ET);
    k_scat<<<SCATB, B, 0, stream>>>(ei, E, ET, chunk, blkoff, bsum, pairs, nbuck);
    k_sortB<<<nbuck, B, 0, stream>>>(pairs, blkoff, bsum, off, csr_src, N, ET, nbuck);

    // ---- layer 1 (input-space aggregation, fused expand; 8 lanes/dst) ----
    k_agg1<<<cdiv((long long)N * 8, B), B, 0, stream>>>(off, csr_src, rech, ad4f,
                                                        W1, b1, out1h, N);

    // ---- layer 2 ----
    k_feat2<<<cdiv((long long)N * 32, B), B, 0, stream>>>(out1h, W2, as2, ad2, h2h,
                                                          a_s2, a_d2, N);
    k_agg2h<<<cdiv((long long)N * 32, B), B, 0, stream>>>(off, csr_src, a_s2, a_d2, h2h, b2,
                                                          Wc1, bc1, Wc2, bc2, out, N);
}

// Round 15
// 99.751 us; speedup vs baseline: 1.7140x; 1.0399x over previous
//
#include <hip/hip_runtime.h>
#include <hip/hip_fp16.h>

#define NEG_SLOPE 0.2f
#define BSHIFT 6          // bucket = 64 consecutive dst ids
#define SCATB 256         // blocks in count/scatter phases

__device__ __forceinline__ float elu1(float v) { return v > 0.f ? v : expm1f(v); }
__device__ __forceinline__ float lrelu(float v) { return v > 0.f ? v : NEG_SLOPE * v; }

// global exclusive offset of scan element j, from scan1 partials + scanned block sums
__device__ __forceinline__ int ge_off(const int* __restrict__ blkoff,
                                      const int* __restrict__ bsum2, int j) {
    if (j == 0) return 0;
    int b = (j - 1) >> 8;            // scan1 block of element j-1 (256/block)
    int v = blkoff[j];
    if (b >= 1) v += bsum2[b - 1];
    return v;
}

// ---------------- CSR build: exact-offset bucketing (no global atomics) ----------------

// Fused: blocks [0,SCATB) bucket histogram; [SCATB, SCATB+nAttn) attn1+record pack.
__global__ __launch_bounds__(256) void k_cnt_attn(
    const int* __restrict__ ei, int E, int ET, int chunk,
    int* __restrict__ Cmat, int nbuck,
    const float* __restrict__ x, const float* __restrict__ W1,
    const float* __restrict__ att_s, const float* __restrict__ att_d,
    __half* __restrict__ rech, float4* __restrict__ ad4f, int N) {
    __shared__ int hist[784];
    __shared__ float Ps[5][4], Pd[5][4];
    if (blockIdx.x < SCATB) {
        for (int i = threadIdx.x; i < nbuck; i += 256) hist[i] = 0;
        __syncthreads();
        int k = blockIdx.x;
        int e0 = k * chunk, e1 = min(e0 + chunk, ET);
        for (int e = e0 + threadIdx.x; e < e1; e += 256) {
            int d = (e < E) ? ei[E + e] : e - E;
            atomicAdd(&hist[d >> BSHIFT], 1);
        }
        __syncthreads();
        for (int i = threadIdx.x; i < nbuck; i += 256)
            Cmat[i * SCATB + k] = hist[i];
    } else {
        // ---- attn1: packed fp16 record rech[16] = {as0..3, x0..4, pad} (32B slot) ----
        if (threadIdx.x < 40) {
            int pair = threadIdx.x & 1, idx = threadIdx.x >> 1;
            int k = idx >> 2, h = idx & 3;
            const float* att = pair ? att_d : att_s;
            float r = 0.f;
#pragma unroll
            for (int c = 0; c < 32; ++c) r = fmaf(W1[k * 128 + h * 32 + c], att[h * 32 + c], r);
            if (pair) Pd[k][h] = r; else Ps[k][h] = r;
        }
        __syncthreads();
        int n = (blockIdx.x - SCATB) * 256 + threadIdx.x;
        if (n >= N) return;
        float xv[5];
#pragma unroll
        for (int k = 0; k < 5; ++k) xv[k] = x[(size_t)n * 5 + k];
        float s0 = 0, s1 = 0, s2 = 0, s3 = 0, d0 = 0, d1 = 0, d2 = 0, d3 = 0;
#pragma unroll
        for (int k = 0; k < 5; ++k) {
            s0 = fmaf(xv[k], Ps[k][0], s0); s1 = fmaf(xv[k], Ps[k][1], s1);
            s2 = fmaf(xv[k], Ps[k][2], s2); s3 = fmaf(xv[k], Ps[k][3], s3);
            d0 = fmaf(xv[k], Pd[k][0], d0); d1 = fmaf(xv[k], Pd[k][1], d1);
            d2 = fmaf(xv[k], Pd[k][2], d2); d3 = fmaf(xv[k], Pd[k][3], d3);
        }
        __half2 a[4];
        a[0] = __floats2half2_rn(s0, s1);
        a[1] = __floats2half2_rn(s2, s3);
        a[2] = __floats2half2_rn(xv[0], xv[1]);
        a[3] = __floats2half2_rn(xv[2], xv[3]);
        __half2 t2[2];
        t2[0] = __floats2half2_rn(xv[4], 0.f);
        t2[1] = __floats2half2_rn(0.f, 0.f);
        *(float4*)(rech + (size_t)n * 16)     = *(float4*)a;
        *(float2*)(rech + (size_t)n * 16 + 8) = *(float2*)t2;
        ad4f[n] = make_float4(d0, d1, d2, d3);
    }
}

// per-block inclusive scan -> blkoff[i+1] (partial), block totals -> bsum
__global__ __launch_bounds__(256) void k_scan1(
    const int* __restrict__ Cmat, int* __restrict__ blkoff, int* __restrict__ bsum, int M) {
    __shared__ int ws4[4], wsoff[4];
    int i = blockIdx.x * 256 + threadIdx.x;
    int lane = threadIdx.x & 63, w = threadIdx.x >> 6;
    int v = (i < M) ? Cmat[i] : 0;
    int sc = v;
#pragma unroll
    for (int m = 1; m < 64; m <<= 1) {
        int t = __shfl_up(sc, m, 64);
        if (lane >= m) sc += t;
    }
    if (lane == 63) ws4[w] = sc;
    __syncthreads();
    if (threadIdx.x == 0) {
        int r = 0;
#pragma unroll
        for (int j = 0; j < 4; ++j) { wsoff[j] = r; r += ws4[j]; }
        bsum[blockIdx.x] = r;
    }
    __syncthreads();
    if (i < M) blkoff[i + 1] = sc + wsoff[w];
    if (i == 0) blkoff[0] = 0;
}

// scan block totals (nb <= 1024), 16-wave block, inclusive in-place; also off[N]=ET
__global__ __launch_bounds__(1024) void k_scan2(
    int* __restrict__ bsum, int nb, int* __restrict__ off, int N, int ET) {
    __shared__ int wsum[16];
    int i = threadIdx.x, lane = i & 63, w = i >> 6;
    if (i == 0) off[N] = ET;
    int v = (i < nb) ? bsum[i] : 0, sc = v;
#pragma unroll
    for (int m = 1; m < 64; m <<= 1) {
        int t = __shfl_up(sc, m, 64);
        if (lane >= m) sc += t;
    }
    if (lane == 63) wsum[w] = sc;
    __syncthreads();
    if (w == 0 && lane < 16) {
        int s2 = wsum[lane];
#pragma unroll
        for (int m = 1; m < 16; m <<= 1) {
            int t = __shfl_up(s2, m, 16);
            if (lane >= m) s2 += t;
        }
        wsum[lane] = s2;
    }
    __syncthreads();
    int carry = (w == 0) ? 0 : wsum[w - 1];
    if (i < nb) bsum[i] = carry + sc;
}

__global__ __launch_bounds__(256) void k_scat(
    const int* __restrict__ ei, int E, int ET, int chunk,
    const int* __restrict__ blkoff, const int* __restrict__ bsum2,
    unsigned* __restrict__ pairs, int nbuck) {
    __shared__ int cur[784];
    int k = blockIdx.x;
    for (int i = threadIdx.x; i < nbuck; i += 256)
        cur[i] = ge_off(blkoff, bsum2, i * SCATB + k);
    __syncthreads();
    int e0 = k * chunk, e1 = min(e0 + chunk, ET);
    for (int e = e0 + threadIdx.x; e < e1; e += 256) {
        int s, d;
        if (e < E) { s = ei[e]; d = ei[E + e]; } else { s = d = e - E; }
        int p = atomicAdd(&cur[d >> BSHIFT], 1);
        pairs[p] = (unsigned)s | ((unsigned)(d & 63) << 16);   // src < 65536
    }
}

// per-bucket LDS counting sort, single pass over pairs (LDS-staged)
__global__ __launch_bounds__(256) void k_sortB(
    const unsigned* __restrict__ pairs, const int* __restrict__ blkoff,
    const int* __restrict__ bsum2, int* __restrict__ off,
    int* __restrict__ csr_src, int N, int ET, int nbuck) {
    __shared__ int hist[64], cur[64];
    __shared__ unsigned pl[1536];
    int b = blockIdx.x;
    int base = ge_off(blkoff, bsum2, b * SCATB);
    int end  = (b + 1 < nbuck) ? ge_off(blkoff, bsum2, (b + 1) * SCATB) : ET;
    int cnt = end - base;
    int stg = min(cnt, 1536);
    int dstBase = b << BSHIFT;
    if (threadIdx.x < 64) hist[threadIdx.x] = 0;
    for (int i = threadIdx.x; i < stg; i += 256) pl[i] = pairs[base + i];
    __syncthreads();
    for (int i = threadIdx.x; i < cnt; i += 256) {
        unsigned pr = (i < stg) ? pl[i] : pairs[base + i];
        atomicAdd(&hist[pr >> 16], 1);
    }
    __syncthreads();
    if (threadIdx.x < 64) {
        int v = hist[threadIdx.x], sc = v;
#pragma unroll
        for (int m = 1; m < 64; m <<= 1) {
            int t = __shfl_up(sc, m, 64);
            if (threadIdx.x >= m) sc += t;
        }
        int ex = sc - v;
        cur[threadIdx.x] = ex;
        int d = dstBase + threadIdx.x;
        if (d < N) off[d] = base + ex;
    }
    __syncthreads();
    for (int i = threadIdx.x; i < cnt; i += 256) {
        unsigned pr = (i < stg) ? pl[i] : pairs[base + i];
        int r = atomicAdd(&cur[pr >> 16], 1);
        csr_src[base + r] = (int)(pr & 0xFFFFu);
    }
}

// ---------------- layer 1 ----------------

// 8-lane group per dst: gathers 32B fp16 records, 3-step butterfly (24 values),
// fused expand with float4 LDS reads; lane l owns head l>>1, channels l*16..+15.
__global__ __launch_bounds__(256) void k_agg1(
    const int* __restrict__ off, const int* __restrict__ csr_src,
    const __half* __restrict__ rech, const float4* __restrict__ ad4f,
    const float* __restrict__ W1, const float* __restrict__ b1,
    __half* __restrict__ out1h, int N) {
    __shared__ float Wl[5 * 128];
    __shared__ float b1l[128];
    for (int i = threadIdx.x; i < 5 * 128; i += 256) Wl[i] = W1[i];
    if (threadIdx.x < 128) b1l[threadIdx.x] = b1[threadIdx.x];
    __syncthreads();
    int g = (blockIdx.x * 256 + threadIdx.x) >> 3;
    int lane = threadIdx.x & 7;
    if (g >= N) return;
    int p0 = off[g], p1 = off[g + 1];
    float4 ad = ad4f[g];
    float den0 = 0, den1 = 0, den2 = 0, den3 = 0;
    float acc[4][5] = {};
    for (int p = p0 + lane; p < p1; p += 8) {
        int s = csr_src[p];
        const __half* r = rech + (size_t)s * 16;
        float4 q = *(const float4*)r;          // halves 0..7: as0..3, x0..3
        const __half2* hp = (const __half2*)&q;
        float2 as01 = __half22float2(hp[0]);
        float2 as23 = __half22float2(hp[1]);
        float2 x01  = __half22float2(hp[2]);
        float2 x23  = __half22float2(hp[3]);
        float  x4   = __half2float(r[8]);
        float v0 = __expf(lrelu(as01.x + ad.x));
        float v1 = __expf(lrelu(as01.y + ad.y));
        float v2 = __expf(lrelu(as23.x + ad.z));
        float v3 = __expf(lrelu(as23.y + ad.w));
        den0 += v0; den1 += v1; den2 += v2; den3 += v3;
        float xk[5] = {x01.x, x01.y, x23.x, x23.y, x4};
#pragma unroll
        for (int k = 0; k < 5; ++k) {
            acc[0][k] = fmaf(v0, xk[k], acc[0][k]);
            acc[1][k] = fmaf(v1, xk[k], acc[1][k]);
            acc[2][k] = fmaf(v2, xk[k], acc[2][k]);
            acc[3][k] = fmaf(v3, xk[k], acc[3][k]);
        }
    }
#pragma unroll
    for (int m = 4; m; m >>= 1) {
        den0 += __shfl_xor(den0, m, 8); den1 += __shfl_xor(den1, m, 8);
        den2 += __shfl_xor(den2, m, 8); den3 += __shfl_xor(den3, m, 8);
#pragma unroll
        for (int h = 0; h < 4; ++h)
#pragma unroll
            for (int k = 0; k < 5; ++k) acc[h][k] += __shfl_xor(acc[h][k], m, 8);
    }
    int h = lane >> 1;
    float dh = (h == 0) ? den0 : (h == 1) ? den1 : (h == 2) ? den2 : den3;
    float ih = 1.f / dh;
    float ag[5];
#pragma unroll
    for (int k = 0; k < 5; ++k) {
        float av = (h == 0) ? acc[0][k] : (h == 1) ? acc[1][k]
                 : (h == 2) ? acc[2][k] : acc[3][k];
        ag[k] = av * ih;
    }
    int c0 = lane * 16;
    float o[16];
    {
        const float4* b4 = (const float4*)(b1l + c0);
#pragma unroll
        for (int j = 0; j < 4; ++j) *(float4*)&o[j * 4] = b4[j];
    }
#pragma unroll
    for (int k = 0; k < 5; ++k) {
        const float4* w4 = (const float4*)(Wl + k * 128 + c0);
        float a = ag[k];
#pragma unroll
        for (int j = 0; j < 4; ++j) {
            float4 wv = w4[j];
            o[j * 4 + 0] = fmaf(a, wv.x, o[j * 4 + 0]);
            o[j * 4 + 1] = fmaf(a, wv.y, o[j * 4 + 1]);
            o[j * 4 + 2] = fmaf(a, wv.z, o[j * 4 + 2]);
            o[j * 4 + 3] = fmaf(a, wv.w, o[j * 4 + 3]);
        }
    }
    __half2 ph[8];
#pragma unroll
    for (int j = 0; j < 8; ++j)
        ph[j] = __floats2half2_rn(elu1(o[2 * j]), elu1(o[2 * j + 1]));
    float4* op = (float4*)(out1h + (size_t)g * 128 + c0);
    op[0] = ((float4*)ph)[0];
    op[1] = ((float4*)ph)[1];
}

// ---------------- layer 2 ----------------

// h2 = out1 @ W2 (128 -> 32) + attention dots. W2 in LDS as fp16 transposed
// [c][k] stride 132; read as uint2 (4 halves) -> 32 DS instrs/thread (was 64).
__global__ __launch_bounds__(256) void k_feat2(
    const __half* __restrict__ out1h, const float* __restrict__ W2,
    const float* __restrict__ att_s, const float* __restrict__ att_d,
    __half* __restrict__ h2h, float* __restrict__ a_s, float* __restrict__ a_d, int N) {
    __shared__ __half Wt[32 * 132];
    for (int i = threadIdx.x; i < 4096; i += 256) {
        int k = i >> 5, c = i & 31;
        Wt[c * 132 + k] = __float2half_rn(W2[i]);
    }
    __syncthreads();
    int t = blockIdx.x * 256 + threadIdx.x;
    int n = t >> 5, c = t & 31;
    if (n >= N) return;
    const float4* hr4 = (const float4*)(out1h + (size_t)n * 128);
    const uint2* wrow2 = (const uint2*)(Wt + c * 132);   // 264B stride, 8B-aligned
    float acc = 0.f;
#pragma unroll
    for (int k4 = 0; k4 < 16; ++k4) {
        float4 q = hr4[k4];
        const __half2* hp = (const __half2*)&q;
        uint2 wa = wrow2[k4 * 2 + 0];
        uint2 wb = wrow2[k4 * 2 + 1];
        __half2 w0 = *(__half2*)&wa.x, w1 = *(__half2*)&wa.y;
        __half2 w2 = *(__half2*)&wb.x, w3 = *(__half2*)&wb.y;
        float2 f, wv;
        f = __half22float2(hp[0]); wv = __half22float2(w0);
        acc = fmaf(f.x, wv.x, acc); acc = fmaf(f.y, wv.y, acc);
        f = __half22float2(hp[1]); wv = __half22float2(w1);
        acc = fmaf(f.x, wv.x, acc); acc = fmaf(f.y, wv.y, acc);
        f = __half22float2(hp[2]); wv = __half22float2(w2);
        acc = fmaf(f.x, wv.x, acc); acc = fmaf(f.y, wv.y, acc);
        f = __half22float2(hp[3]); wv = __half22float2(w3);
        acc = fmaf(f.x, wv.x, acc); acc = fmaf(f.y, wv.y, acc);
    }
    h2h[(size_t)n * 32 + c] = __float2half_rn(acc);
    float as = acc * att_s[c], ad = acc * att_d[c];
#pragma unroll
    for (int m = 16; m; m >>= 1) {
        as += __shfl_xor(as, m, 32);
        ad += __shfl_xor(ad, m, 32);
    }
    if (c == 0) { a_s[n] = as; a_d[n] = ad; }
}

// ---------------- layer-2 aggregation + fused MLP head ----------------
// (s,w) staged once in LDS per 32-edge chunk; 8-deep pipeline for full chunks,
// 4-edge tail (avg degree 17 -> fewer wasted row-gathers than pad-to-8).
__global__ __launch_bounds__(256) void k_agg2h(
    const int* __restrict__ off, const int* __restrict__ csr_src,
    const float* __restrict__ a_s, const float* __restrict__ a_d,
    const __half* __restrict__ h2h, const float* __restrict__ b2,
    const float* __restrict__ Wc1, const float* __restrict__ bc1,
    const float* __restrict__ Wc2, const float* __restrict__ bc2,
    float* __restrict__ out, int N) {
    __shared__ float Wl[512];
    __shared__ float b2l[32], b1l[16], w2l[16];
    __shared__ uint2 wsb[256];          // per-thread (s, w) staging
    for (int i = threadIdx.x; i < 512; i += 256) Wl[i] = Wc1[i];
    if (threadIdx.x < 32) b2l[threadIdx.x] = b2[threadIdx.x];
    if (threadIdx.x < 16) {
        b1l[threadIdx.x] = bc1[threadIdx.x];
        w2l[threadIdx.x] = Wc2[threadIdx.x];
    }
    __syncthreads();
    int g = (blockIdx.x * 256 + threadIdx.x) >> 5;
    int lane = threadIdx.x & 31;
    int gl = threadIdx.x >> 5;          // group index within block
    if (g >= N) return;
    int p0 = off[g], p1 = off[g + 1];
    float ad = a_d[g];
    float acc = 0.f, den = 0.f;
    const uint4* wp = (const uint4*)(wsb + (gl << 5));
    for (int base = p0; base < p1; base += 32) {
        int rem = p1 - base;
        int s = g;                 // safe index for padded lanes
        float w = 0.f;
        if (lane < rem) {
            s = csr_src[base + lane];           // coalesced
            w = __expf(lrelu(a_s[s] + ad));     // one exp per edge
        }
        den += w;
        wsb[threadIdx.x] = make_uint2((unsigned)s, __float_as_uint(w));
        // same-wave LDS write->read: in-order DS pipe, per-tid slots, no barrier
        int cnt = min(rem, 32);
        int rc = (cnt + 3) & ~3;   // pad to multiple of 4 (w=0 beyond cnt)
        int j = 0;
        for (; j + 8 <= rc; j += 8) {
#pragma unroll
            for (int jj = 0; jj < 4; ++jj) {
                uint4 q = wp[(j >> 1) + jj];    // 2 edges per b128 broadcast
                float w0 = __uint_as_float(q.y);
                float w1 = __uint_as_float(q.w);
                float h0 = __half2float(h2h[(size_t)q.x * 32 + lane]);
                float h1 = __half2float(h2h[(size_t)q.z * 32 + lane]);
                acc = fmaf(w0, h0, acc);
                acc = fmaf(w1, h1, acc);
            }
        }
        for (; j < rc; j += 4) {
#pragma unroll
            for (int jj = 0; jj < 2; ++jj) {
                uint4 q = wp[(j >> 1) + jj];
                float w0 = __uint_as_float(q.y);
                float w1 = __uint_as_float(q.w);
                float h0 = __half2float(h2h[(size_t)q.x * 32 + lane]);
                float h1 = __half2float(h2h[(size_t)q.z * 32 + lane]);
                acc = fmaf(w0, h0, acc);
                acc = fmaf(w1, h1, acc);
            }
        }
    }
#pragma unroll
    for (int m = 16; m; m >>= 1) den += __shfl_xor(den, m, 32);
    float z = elu1(fmaf(acc, 1.f / den, b2l[lane]));
    float y = b1l[lane & 15];
#pragma unroll
    for (int c = 0; c < 32; ++c) {
        float zc = __shfl(z, c, 32);
        y = fmaf(zc, Wl[c * 16 + (lane & 15)], y);
    }
    y = fmaxf(y, 0.f);
    float t = (lane < 16) ? y * w2l[lane] : 0.f;
#pragma unroll
    for (int m = 8; m; m >>= 1) t += __shfl_xor(t, m, 32);
    if (lane == 0) out[g] = t + bc2[0];
}

extern "C" void kernel_launch(void* const* d_in, const int* in_sizes, int n_in,
                              void* d_out, int out_size, void* d_ws, size_t ws_size,
                              hipStream_t stream) {
    const float* x   = (const float*)d_in[0];
    const int*   ei  = (const int*)d_in[1];
    const float* W1  = (const float*)d_in[2];
    const float* as1 = (const float*)d_in[3];
    const float* ad1 = (const float*)d_in[4];
    const float* b1  = (const float*)d_in[5];
    const float* W2  = (const float*)d_in[6];
    const float* as2 = (const float*)d_in[7];
    const float* ad2 = (const float*)d_in[8];
    const float* b2  = (const float*)d_in[9];
    const float* Wc1 = (const float*)d_in[10];
    const float* bc1 = (const float*)d_in[11];
    const float* Wc2 = (const float*)d_in[12];
    const float* bc2 = (const float*)d_in[13];
    float* out = (float*)d_out;

    const int N = out_size;                  // 50000
    const int E = in_sizes[1] / 2;           // 800000
    const int ET = E + N;                    // + self loops
    const int nbuck = (N + 63) >> BSHIFT;    // 782
    const int M = nbuck * SCATB;             // 200192 scan elements
    const int chunk = (ET + SCATB - 1) / SCATB;

    auto cdiv = [](long long a, long long b) { return (int)((a + b - 1) / b); };
    const int B = 256;
    const int NB2 = cdiv(M, B);              // 782 <= 1024
    const int nAttn = cdiv(N, B);            // 196

    // Workspace layout (float units; all half counts even -> aligned)
    float*    ws    = (float*)d_ws;
    __half*   out1h = (__half*)ws;                       // N*128 halves (N*64 f)
    __half*   h2h   = (__half*)(ws + (size_t)N * 64);    // N*32 halves (N*16 f)
    __half*   rech  = (__half*)(ws + (size_t)N * 80);    // N*16 halves (N*8 f)
    float4*   ad4f  = (float4*)(ws + (size_t)N * 88);    // N float4
    float*    a_s2  = ws + (size_t)N * 92;               // N
    float*    a_d2  = a_s2 + N;                          // N
    int*      off   = (int*)(a_d2 + N);                  // N+1
    int*      csr_src = off + (N + 2);                   // ET
    int*      Cmat  = csr_src + ET;                      // M
    int*      blkoff = Cmat + M;                         // M+2
    int*      bsum  = blkoff + (M + 2);                  // 1024
    unsigned* pairs = (unsigned*)(bsum + 1024);          // ET

    // ---- CSR build (count+attn1 -> 2-level scan -> scatter -> sort) ----
    k_cnt_attn<<<SCATB + nAttn, B, 0, stream>>>(ei, E, ET, chunk, Cmat, nbuck,
                                                x, W1, as1, ad1, rech, ad4f, N);
    k_scan1<<<NB2, B, 0, stream>>>(Cmat, blkoff, bsum, M);
    k_scan2<<<1, 1024, 0, stream>>>(bsum, NB2, off, N, ET);
    k_scat<<<SCATB, B, 0, stream>>>(ei, E, ET, chunk, blkoff, bsum, pairs, nbuck);
    k_sortB<<<nbuck, B, 0, stream>>>(pairs, blkoff, bsum, off, csr_src, N, ET, nbuck);

    // ---- layer 1 (input-space aggregation, fused expand; 8 lanes/dst) ----
    k_agg1<<<cdiv((long long)N * 8, B), B, 0, stream>>>(off, csr_src, rech, ad4f,
                                                        W1, b1, out1h, N);

    // ---- layer 2 ----
    k_feat2<<<cdiv((long long)N * 32, B), B, 0, stream>>>(out1h, W2, as2, ad2, h2h,
                                                          a_s2, a_d2, N);
    k_agg2h<<<cdiv((long long)N * 32, B), B, 0, stream>>>(off, csr_src, a_s2, a_d2, h2h, b2,
                                                          Wc1, bc1, Wc2, bc2, out, N);
}